// Round 7
// baseline (422.755 us; speedup 1.0000x reference)
//
#include <hip/hip_runtime.h>
#include <hip/hip_bf16.h>

#define EPS 1e-6f

typedef float f32x4 __attribute__((ext_vector_type(4)));
typedef short s16x8 __attribute__((ext_vector_type(8)));
typedef unsigned long long u64;
typedef unsigned int u32;

static __device__ __forceinline__ u32 cvt2u(float x, float y) {
  __hip_bfloat162 h = __float22bfloat162_rn(make_float2(x, y));
  union { __hip_bfloat162 h; u32 u; } c; c.h = h; return c.u;
}
static __device__ __forceinline__ uint4 pack8(const f32x4 a, const f32x4 b) {
  uint4 r; r.x = cvt2u(a[0], a[1]); r.y = cvt2u(a[2], a[3]);
  r.z = cvt2u(b[0], b[1]); r.w = cvt2u(b[2], b[3]); return r;
}
static __device__ __forceinline__ float bf2f(unsigned short u) {
  union { u32 u; float f; } c; c.u = ((u32)u) << 16; return c.f;
}
static __device__ __forceinline__ void gload16(const void* g, void* l) {
  __builtin_amdgcn_global_load_lds((const __attribute__((address_space(1))) u32*)g,
                                   (__attribute__((address_space(3))) u32*)l, 16, 0, 0);
}
// XOR swizzle on byte offset (bits 4-6) keyed by row low bits.
// NOTE: must be applied to the FULL logical offset (incl. bit 6). A
// post-swizzle "+ 64" carries into bit 7 when the swizzle set bit 6
// (rows with R&4) — that was round-5's bug. Use "^ (kk<<6)" instead,
// which is exact because the base logical offset has bit 6 clear.
#define SWZ(off, row) ((off) ^ (((row) & 7) << 4))

// ---------------- kernel 1: per-row stats (E + C) and C->bf16 ----------------
// One wave per row. wid<65536: E row -> esqadj. Else: C row -> cbf + cterm.
// Stats computed on bf16-ROUNDED values for consistency with the MFMA dot.
__global__ __launch_bounds__(256) void prep(const float* __restrict__ E,
                                            const float* __restrict__ C,
                                            unsigned short* __restrict__ cbf,
                                            float* __restrict__ cterm,
                                            float* __restrict__ esqadj) {
  const int wid = (blockIdx.x << 2) + (threadIdx.x >> 6);
  const int ln = threadIdx.x & 63;
  const bool isE = wid < 65536;
  const int row = isE ? wid : (wid - 65536);
  const float* p = (isE ? E : C) + ((size_t)row << 9) + (ln << 3);
  f32x4 a = *(const f32x4*)p;
  f32x4 b = *(const f32x4*)(p + 4);
  uint4 packed = pack8(a, b);
  if (!isE) *(uint4*)&cbf[((size_t)row << 9) + (ln << 3)] = packed;
  float sq = 0.f, sm = 0.f;
  const unsigned short* s = (const unsigned short*)&packed;
  #pragma unroll
  for (int e = 0; e < 8; ++e) { float fv = bf2f(s[e]); sq = fmaf(fv, fv, sq); sm += fv; }
  #pragma unroll
  for (int mask = 1; mask <= 32; mask <<= 1) {
    sq += __shfl_xor(sq, mask);
    sm += __shfl_xor(sm, mask);
  }
  if (ln == 0) {
    if (isE) esqadj[row] = sq - (2.0f * EPS) * sm + 512.f * EPS * EPS;
    else     cterm[row]  = sq + (2.0f * EPS) * sm;
  }
}

// ---------------- kernel 2: m97-style 128x128 GEMM tile + per-block argmin ----------------
// 256 thr / 4 waves, wave tile 64x64 (wr=wv>>1, wc=wv&1), acc[4][4] 16x16x32.
// LDS 32KB -> 3 blocks/CU. B via global_load_lds (pre-swizzled global source,
// linear LDS dest, swizzled ds_read). A (fp32) reg-staged issue-early/write-late.
// Result: one atomicMin(u64 key) per row per block; key=(ord(score)<<32)|col.
__global__ __launch_bounds__(256, 3) void assign_kernel(
    const float* __restrict__ E, const unsigned short* __restrict__ cbf,
    const float* __restrict__ cterm, u64* __restrict__ keys) {

  __shared__ __align__(16) unsigned short aBuf[128 * 64];   // 16 KB
  __shared__ __align__(16) unsigned short bBuf[128 * 64];   // 16 KB

  const int tid = threadIdx.x;
  const int wv = tid >> 6, ln = tid & 63;
  const int g = ln >> 4, cc = ln & 15;
  const int wr = wv >> 1, wc = wv & 1;
  const int bx = blockIdx.x >> 3;          // row-block (slow)
  const int by = blockIdx.x & 7;           // col-block (fast -> A-panel reuse in cache)

  // B-DMA per-lane inverse-swizzled source offsets (kt-invariant).
  // Chunk c covers physical LDS bytes [c*1024, c*1024+1024); decode the full
  // physical offset back to (row, logical slot) to build the global source.
  int boff[4];
  #pragma unroll
  for (int i = 0; i < 4; ++i) {
    const int c = (wv << 2) + i;
    const int o = (c << 10) + (ln << 4);
    const int r = o >> 7;
    const int s = ((o >> 4) & 7) ^ (r & 7);
    boff[i] = (r << 10) + (s << 4);        // bytes within cbf col-panel (row stride 1024B)
  }
  const char* Bbase = (const char*)cbf + ((size_t)by << 17);  // by*128 rows * 1024B

  // A staging: thread -> (row, half-row of 32 dims)
  const int arow = tid >> 1, ah = tid & 1;
  const float* Arow = E + ((size_t)((bx << 7) + arow) << 9) + (ah << 5);
  unsigned short* awr = &aBuf[0];
  int awoff[4];
  #pragma unroll
  for (int j = 0; j < 4; ++j)
    awoff[j] = SWZ((arow << 7) + (ah << 6) + (j << 4), arow);

  // fragment read byte offsets (kt-invariant; kk handled by XOR bit 6 below)
  int aro[4], bro[4];
  #pragma unroll
  for (int m = 0; m < 4; ++m) {
    const int R = (wr << 6) + (m << 4) + cc;
    aro[m] = SWZ((R << 7) + (g << 4), R);
    const int Rb = (wc << 6) + (m << 4) + cc;
    bro[m] = SWZ((Rb << 7) + (g << 4), Rb);
  }

  f32x4 acc[4][4];
  #pragma unroll
  for (int m = 0; m < 4; ++m)
    #pragma unroll
    for (int n = 0; n < 4; ++n) acc[m][n] = f32x4{0.f, 0.f, 0.f, 0.f};

  // prologue: A-loads for kt=0
  f32x4 av[8];
  #pragma unroll
  for (int j = 0; j < 8; ++j) av[j] = *(const f32x4*)(Arow + (j << 2));

  for (int kt = 0; kt < 8; ++kt) {
    __syncthreads();                       // A: all reads of previous tile done
    // B tile kt via LDS-DMA (tracked by vmcnt, drained at barrier B)
    #pragma unroll
    for (int i = 0; i < 4; ++i)
      gload16(Bbase + (kt << 7) + boff[i],
              (char*)bBuf + (((wv << 2) + i) << 10));
    // A tile kt: cvt + ds_write from prefetched regs
    #pragma unroll
    for (int j = 0; j < 4; ++j)
      *(uint4*)((char*)awr + awoff[j]) = pack8(av[2 * j], av[2 * j + 1]);
    __syncthreads();                       // B: tile kt fully staged

    // issue A-loads for kt+1 now -> they fly across the MFMA phase
    if (kt < 7) {
      const float* p = Arow + ((kt + 1) << 6);
      #pragma unroll
      for (int j = 0; j < 8; ++j) av[j] = *(const f32x4*)(p + (j << 2));
    }

    #pragma unroll
    for (int kk = 0; kk < 2; ++kk) {
      s16x8 af[4], bfr[4];
      #pragma unroll
      for (int m = 0; m < 4; ++m)
        af[m] = *(const s16x8*)((char*)aBuf + (aro[m] ^ (kk << 6)));
      #pragma unroll
      for (int n = 0; n < 4; ++n)
        bfr[n] = *(const s16x8*)((char*)bBuf + (bro[n] ^ (kk << 6)));
      #pragma unroll
      for (int m = 0; m < 4; ++m)
        #pragma unroll
        for (int n = 0; n < 4; ++n)
          acc[m][n] = __builtin_amdgcn_mfma_f32_16x16x32_bf16(af[m], bfr[n], acc[m][n], 0, 0, 0);
    }
  }

  // ---- epilogue: per-lane fold over n, 16-lane argmin reduce, pack keys ----
  u64 key[16];
  #pragma unroll
  for (int m = 0; m < 4; ++m)
    #pragma unroll
    for (int r = 0; r < 4; ++r) {
      float v = INFINITY; int idx = 0;
      #pragma unroll
      for (int n = 0; n < 4; ++n) {
        const int col = (by << 7) + (wc << 6) + (n << 4) + cc;
        const float s = fmaf(-2.f, acc[m][n][r], cterm[col]);
        if (s < v) { v = s; idx = col; }
      }
      #pragma unroll
      for (int mask = 1; mask <= 8; mask <<= 1) {
        float pv = __shfl_xor(v, mask);
        int   pi = __shfl_xor(idx, mask);
        if (pv < v || (pv == v && pi < idx)) { v = pv; idx = pi; }
      }
      u32 fb = __float_as_uint(v);
      fb = (fb & 0x80000000u) ? ~fb : (fb | 0x80000000u);   // order-preserving
      key[(m << 2) + r] = ((u64)fb << 32) | (u32)idx;
    }

  __syncthreads();                          // done reading aBuf/bBuf
  u64* cmb = (u64*)aBuf;                    // [128][2]
  if (cc == 0) {
    #pragma unroll
    for (int m = 0; m < 4; ++m)
      #pragma unroll
      for (int r = 0; r < 4; ++r) {
        const int row = (wr << 6) + (m << 4) + (g << 2) + r;
        cmb[(row << 1) + wc] = key[(m << 2) + r];
      }
  }
  __syncthreads();
  if (tid < 128) {
    u64 k0 = cmb[tid << 1], k1 = cmb[(tid << 1) + 1];
    atomicMin(&keys[(bx << 7) + tid], k0 < k1 ? k0 : k1);
  }
}

// ---------------- kernel 3: decode keys -> segment atomics ----------------
__global__ __launch_bounds__(256) void post(const u64* __restrict__ keys,
                                            const float* __restrict__ esqadj,
                                            float* __restrict__ sums,
                                            float* __restrict__ counts,
                                            int* __restrict__ maxs) {
  const int n = (blockIdx.x << 8) + threadIdx.x;
  const u64 key = keys[n];
  const u32 ob = (u32)(key >> 32);
  const u32 fb = (ob & 0x80000000u) ? (ob ^ 0x80000000u) : ~ob;
  const float v = __uint_as_float(fb);
  const int k = (int)(key & 0xFFFFFFFFu);
  const float d = sqrtf(fmaxf(v + esqadj[n], 0.f));
  atomicAdd(&sums[k], d);
  atomicAdd(&counts[k], 1.f);
  atomicMax(&maxs[k], __float_as_int(d));
}

// ---------------- kernel 4: final reduction over K=1024 clusters ----------------
__global__ __launch_bounds__(1024) void finalize(const float* __restrict__ sums,
                                                 const float* __restrict__ counts,
                                                 const int* __restrict__ maxs,
                                                 float* __restrict__ out) {
  const int t = threadIdx.x;
  const float cnt = counts[t];
  const float s = sums[t];
  const float mx = fmaxf(__int_as_float(maxs[t]), 0.f);
  float v0 = s / (cnt + 1.0f);
  float v1 = mx;
  float v2 = cnt;
  #pragma unroll
  for (int mask = 1; mask <= 32; mask <<= 1) {
    v0 += __shfl_xor(v0, mask);
    v1 += __shfl_xor(v1, mask);
    v2 += __shfl_xor(v2, mask);
  }
  __shared__ float r0[16], r1[16], r2[16];
  const int wv = t >> 6, ln = t & 63;
  if (ln == 0) { r0[wv] = v0; r1[wv] = v1; r2[wv] = v2; }
  __syncthreads();
  if (t == 0) {
    float a = 0.f, b = 0.f, c = 0.f;
    for (int i = 0; i < 16; ++i) { a += r0[i]; b += r1[i]; c += r2[i]; }
    out[0] = a * (1.f / 1024.f);
    out[1] = b * (1.f / 1024.f);
    out[2] = c * (1.f / 1024.f);
  }
}

extern "C" void kernel_launch(void* const* d_in, const int* in_sizes, int n_in,
                              void* d_out, int out_size, void* d_ws, size_t ws_size,
                              hipStream_t stream) {
  const float* E = (const float*)d_in[0];   // (65536, 512)
  const float* C = (const float*)d_in[1];   // (1024, 512)
  float* out = (float*)d_out;               // 3 floats

  char* ws = (char*)d_ws;
  unsigned short* cbf = (unsigned short*)ws;                 // 1 MB
  float* cterm   = (float*)(ws + (1 << 20));                 // 4 KB
  float* esqadj  = (float*)(ws + (1 << 20) + (4 << 10));     // 256 KB
  u64*   keys    = (u64*)  (ws + (1 << 20) + (260 << 10));   // 512 KB
  float* sums    = (float*)(ws + (1 << 20) + (772 << 10));   // 4 KB
  float* counts  = sums + 1024;                              // 4 KB
  int*   maxs    = (int*)(counts + 1024);                    // 4 KB

  hipMemsetAsync(keys, 0xFF, 65536 * sizeof(u64), stream);
  hipMemsetAsync(sums, 0, 3 * 1024 * sizeof(float), stream);
  prep<<<16640, 256, 0, stream>>>(E, C, cbf, cterm, esqadj);
  assign_kernel<<<4096, 256, 0, stream>>>(E, cbf, cterm, keys);
  post<<<256, 256, 0, stream>>>(keys, esqadj, sums, counts, maxs);
  finalize<<<1, 1024, 0, stream>>>(sums, counts, maxs, out);
}